// Round 1
// baseline (381.534 us; speedup 1.0000x reference)
//
#include <hip/hip_runtime.h>
#include <stdint.h>
#include <math.h>

#define T_SEQ 4096
#define DM 1024
#define NH 16
#define DH 64

typedef unsigned short u16;
typedef __attribute__((ext_vector_type(8))) short bfx8;   // 8 bf16 = 4 VGPR
typedef __attribute__((ext_vector_type(4))) float f4;     // MFMA C/D

__device__ inline u16 f2bf(float f) {
  uint32_t u = __float_as_uint(f);
  u = (u + 0x7fffu + ((u >> 16) & 1u)) >> 16;
  return (u16)u;
}

// async global->LDS, 16B per lane. LDS dest must be uniform-base + lane*16.
__device__ inline void gl_lds16(const void* g, void* l) {
  __builtin_amdgcn_global_load_lds(
      (__attribute__((address_space(1))) uint32_t*)const_cast<void*>(g),
      (__attribute__((address_space(3))) uint32_t*)l, 16, 0, 0);
}

// ---------------- fp32 -> bf16 convert (vectorized) ----------------
__global__ __launch_bounds__(256) void cvt_kernel(const float* __restrict__ src,
                                                  u16* __restrict__ dst, int n8) {
  int i = blockIdx.x * 256 + threadIdx.x;
  if (i >= n8) return;
  const float4* s = (const float4*)src + (size_t)i * 2;
  float4 a = s[0], b = s[1];
  union { u16 u[8]; bfx8 v; } o;
  o.u[0] = f2bf(a.x); o.u[1] = f2bf(a.y); o.u[2] = f2bf(a.z); o.u[3] = f2bf(a.w);
  o.u[4] = f2bf(b.x); o.u[5] = f2bf(b.y); o.u[6] = f2bf(b.z); o.u[7] = f2bf(b.w);
  *(bfx8*)(dst + (size_t)i * 8) = o.v;
}

// ---------------- QKV projection GEMM (NT): y = x @ W^T + b ----------------
// 128x128 tile, BK=32, 4 waves (2x2), 16x16x32 bf16 MFMA.
// mode 0: q out [h][t][d], *0.125; mode 1: k out [h][t][d]; mode 2: v out [h][d][t].
__global__ __launch_bounds__(256) void gemm_qkv(
    const u16* __restrict__ xb,
    const u16* __restrict__ wq, const u16* __restrict__ wk, const u16* __restrict__ wv,
    const float* __restrict__ bq, const float* __restrict__ bk, const float* __restrict__ bv,
    u16* __restrict__ qo, u16* __restrict__ ko, u16* __restrict__ vo) {
  __shared__ u16 sA[128 * 32];
  __shared__ u16 sB[128 * 32];
  const int mode = blockIdx.z;
  const u16* w = (mode == 0) ? wq : (mode == 1) ? wk : wv;
  const float* bias = (mode == 0) ? bq : (mode == 1) ? bk : bv;
  const int tid = threadIdx.x, lane = tid & 63, wid = tid >> 6;
  const int wr = wid >> 1, wc = wid & 1;
  const int row0 = blockIdx.y * 128, col0 = blockIdx.x * 128;
  f4 acc[4][4] = {};

  for (int kt = 0; kt < DM / 32; ++kt) {
#pragma unroll
    for (int i = 0; i < 2; ++i) {  // stage A and B tiles (swizzled source, linear dest)
      int c = i * 4 + wid;                 // 1KB chunk 0..7
      int r = c * 16 + (lane >> 2);        // tile row 0..127 (64B rows)
      int s = (lane & 3) ^ ((r >> 1) & 3); // source slot pre-swizzle
      gl_lds16(xb + (size_t)(row0 + r) * DM + kt * 32 + s * 8, &sA[c * 512 + lane * 8]);
      gl_lds16(w  + (size_t)(col0 + r) * DM + kt * 32 + s * 8, &sB[c * 512 + lane * 8]);
    }
    __syncthreads();
    bfx8 a[4], b[4];
#pragma unroll
    for (int t = 0; t < 4; ++t) {
      int ra = wr * 64 + t * 16 + (lane & 15);
      a[t] = *(const bfx8*)&sA[ra * 32 + (((lane >> 4) ^ ((ra >> 1) & 3)) * 8)];
      int rb = wc * 64 + t * 16 + (lane & 15);
      b[t] = *(const bfx8*)&sB[rb * 32 + (((lane >> 4) ^ ((rb >> 1) & 3)) * 8)];
    }
#pragma unroll
    for (int mt = 0; mt < 4; ++mt)
#pragma unroll
      for (int nt = 0; nt < 4; ++nt)
        acc[mt][nt] = __builtin_amdgcn_mfma_f32_16x16x32_bf16(a[mt], b[nt], acc[mt][nt], 0, 0, 0);
    __syncthreads();
  }

#pragma unroll
  for (int mt = 0; mt < 4; ++mt) {
#pragma unroll
    for (int nt = 0; nt < 4; ++nt) {
      int n = col0 + wc * 64 + nt * 16 + (lane & 15);
      float bv_ = bias[n];
      int h = n >> 6, d = n & 63;
#pragma unroll
      for (int r = 0; r < 4; ++r) {
        int m = row0 + wr * 64 + mt * 16 + (lane >> 4) * 4 + r;  // C/D: col=lane&15, row=(lane>>4)*4+r
        float v = acc[mt][nt][r] + bv_;
        if (mode == 0)      qo[(size_t)h * (T_SEQ * DH) + (size_t)m * DH + d] = f2bf(v * 0.125f);
        else if (mode == 1) ko[(size_t)h * (T_SEQ * DH) + (size_t)m * DH + d] = f2bf(v);
        else                vo[(size_t)h * (DH * T_SEQ) + (size_t)d * T_SEQ + m] = f2bf(v);
      }
    }
  }
}

// ---------------- output projection GEMM: out = ao @ Wo^T + bo (fp32 out) ----------------
__global__ __launch_bounds__(256) void gemm_out(
    const u16* __restrict__ ab, const u16* __restrict__ wo,
    const float* __restrict__ bo, float* __restrict__ out) {
  __shared__ u16 sA[128 * 32];
  __shared__ u16 sB[128 * 32];
  const int tid = threadIdx.x, lane = tid & 63, wid = tid >> 6;
  const int wr = wid >> 1, wc = wid & 1;
  const int row0 = blockIdx.y * 128, col0 = blockIdx.x * 128;
  f4 acc[4][4] = {};

  for (int kt = 0; kt < DM / 32; ++kt) {
#pragma unroll
    for (int i = 0; i < 2; ++i) {
      int c = i * 4 + wid;
      int r = c * 16 + (lane >> 2);
      int s = (lane & 3) ^ ((r >> 1) & 3);
      gl_lds16(ab + (size_t)(row0 + r) * DM + kt * 32 + s * 8, &sA[c * 512 + lane * 8]);
      gl_lds16(wo + (size_t)(col0 + r) * DM + kt * 32 + s * 8, &sB[c * 512 + lane * 8]);
    }
    __syncthreads();
    bfx8 a[4], b[4];
#pragma unroll
    for (int t = 0; t < 4; ++t) {
      int ra = wr * 64 + t * 16 + (lane & 15);
      a[t] = *(const bfx8*)&sA[ra * 32 + (((lane >> 4) ^ ((ra >> 1) & 3)) * 8)];
      int rb = wc * 64 + t * 16 + (lane & 15);
      b[t] = *(const bfx8*)&sB[rb * 32 + (((lane >> 4) ^ ((rb >> 1) & 3)) * 8)];
    }
#pragma unroll
    for (int mt = 0; mt < 4; ++mt)
#pragma unroll
      for (int nt = 0; nt < 4; ++nt)
        acc[mt][nt] = __builtin_amdgcn_mfma_f32_16x16x32_bf16(a[mt], b[nt], acc[mt][nt], 0, 0, 0);
    __syncthreads();
  }

#pragma unroll
  for (int mt = 0; mt < 4; ++mt) {
#pragma unroll
    for (int nt = 0; nt < 4; ++nt) {
      int n = col0 + wc * 64 + nt * 16 + (lane & 15);
      float bv_ = bo[n];
#pragma unroll
      for (int r = 0; r < 4; ++r) {
        int m = row0 + wr * 64 + mt * 16 + (lane >> 4) * 4 + r;
        out[(size_t)m * DM + n] = acc[mt][nt][r] + bv_;
      }
    }
  }
}

// ---------------- flash attention ----------------
// grid (T/64, H); 4 waves, 16 q-rows per wave; KVBLK=64; Q pre-scaled by 1/8.
// K in [h][t][d], V transposed [h][d][t]; both staged in LDS with XOR swizzle
// (linear LDS dest for global_load_lds, swizzle applied to global source + LDS read).
__global__ __launch_bounds__(256) void attn_kernel(
    const u16* __restrict__ qb, const u16* __restrict__ kb,
    const u16* __restrict__ vb, u16* __restrict__ ao) {
  __shared__ u16 sK[64 * 64];
  __shared__ u16 sV[64 * 64];
  __shared__ u16 sP[4 * 16 * 64];
  const int tid = threadIdx.x, lane = tid & 63, wid = tid >> 6;
  const int h = blockIdx.y;
  const int qr0 = blockIdx.x * 64 + wid * 16;
  const size_t hoff = (size_t)h * (T_SEQ * DH);

  bfx8 qf[2];
#pragma unroll
  for (int ks = 0; ks < 2; ++ks)  // A-frag: row=lane&15, k=(lane>>4)*8+j
    qf[ks] = *(const bfx8*)(qb + hoff + (size_t)(qr0 + (lane & 15)) * DH + ks * 32 + (lane >> 4) * 8);

  f4 oacc[4] = {};
  float mrow[4] = {-INFINITY, -INFINITY, -INFINITY, -INFINITY};
  float lrow[4] = {0.f, 0.f, 0.f, 0.f};
  u16* myP = &sP[wid * 1024];

  for (int kt = 0; kt < T_SEQ / 64; ++kt) {
#pragma unroll
    for (int i = 0; i < 2; ++i) {  // stage K [kv][d] and V^T [d][kv], 128B rows
      int c = i * 4 + wid;              // 1KB chunk 0..7
      int r = c * 8 + (lane >> 3);      // tile row 0..63
      int s = (lane & 7) ^ (r & 7);     // pre-swizzled source slot
      gl_lds16(kb + hoff + (size_t)(kt * 64 + r) * DH + s * 8, &sK[c * 512 + lane * 8]);
      gl_lds16(vb + hoff + (size_t)r * T_SEQ + kt * 64 + s * 8, &sV[c * 512 + lane * 8]);
    }
    __syncthreads();

    // S = Q K^T  (S row=q, col=kv)
    f4 sacc[4] = {};
#pragma unroll
    for (int tn = 0; tn < 4; ++tn) {
#pragma unroll
      for (int ks = 0; ks < 2; ++ks) {
        int rk = tn * 16 + (lane & 15);
        int sl = (ks * 4 + (lane >> 4)) ^ (rk & 7);
        bfx8 kf = *(const bfx8*)&sK[rk * 64 + sl * 8];
        sacc[tn] = __builtin_amdgcn_mfma_f32_16x16x32_bf16(qf[ks], kf, sacc[tn], 0, 0, 0);
      }
    }

    // online softmax over the 64 keys of this tile
#pragma unroll
    for (int r = 0; r < 4; ++r) {
      float tm = fmaxf(fmaxf(sacc[0][r], sacc[1][r]), fmaxf(sacc[2][r], sacc[3][r]));
      tm = fmaxf(tm, __shfl_xor(tm, 1));
      tm = fmaxf(tm, __shfl_xor(tm, 2));
      tm = fmaxf(tm, __shfl_xor(tm, 4));
      tm = fmaxf(tm, __shfl_xor(tm, 8));
      float mnew = fmaxf(mrow[r], tm);
      float fsc = __expf(mrow[r] - mnew);
      float psum = 0.f;
      int qrow = (lane >> 4) * 4 + r;
#pragma unroll
      for (int tn = 0; tn < 4; ++tn) {
        float p = __expf(sacc[tn][r] - mnew);
        psum += p;
        int k = tn * 16 + (lane & 15);
        myP[qrow * 64 + (((k >> 3) ^ (qrow & 7)) * 8) + (k & 7)] = f2bf(p);
      }
      psum += __shfl_xor(psum, 1);
      psum += __shfl_xor(psum, 2);
      psum += __shfl_xor(psum, 4);
      psum += __shfl_xor(psum, 8);
      lrow[r] = lrow[r] * fsc + psum;
      mrow[r] = mnew;
#pragma unroll
      for (int td = 0; td < 4; ++td) oacc[td][r] *= fsc;
    }

    // O += P V   (A-frag = P rows, B-frag = V^T rows)
#pragma unroll
    for (int ks = 0; ks < 2; ++ks) {
      int qr = lane & 15;
      int slp = (ks * 4 + (lane >> 4)) ^ (qr & 7);
      bfx8 pf = *(const bfx8*)&myP[qr * 64 + slp * 8];
#pragma unroll
      for (int td = 0; td < 4; ++td) {
        int rv = td * 16 + (lane & 15);
        int sv = (ks * 4 + (lane >> 4)) ^ (rv & 7);
        bfx8 vf = *(const bfx8*)&sV[rv * 64 + sv * 8];
        oacc[td] = __builtin_amdgcn_mfma_f32_16x16x32_bf16(pf, vf, oacc[td], 0, 0, 0);
      }
    }
    __syncthreads();
  }

#pragma unroll
  for (int r = 0; r < 4; ++r) {
    float inv = 1.0f / lrow[r];
    int t = qr0 + (lane >> 4) * 4 + r;
#pragma unroll
    for (int td = 0; td < 4; ++td)
      ao[(size_t)t * DM + h * DH + td * 16 + (lane & 15)] = f2bf(oacc[td][r] * inv);
  }
}

extern "C" void kernel_launch(void* const* d_in, const int* in_sizes, int n_in,
                              void* d_out, int out_size, void* d_ws, size_t ws_size,
                              hipStream_t stream) {
  const float* x  = (const float*)d_in[0];
  const float* Wq = (const float*)d_in[1];
  const float* bq = (const float*)d_in[2];
  const float* Wk = (const float*)d_in[3];
  const float* bk = (const float*)d_in[4];
  const float* Wv = (const float*)d_in[5];
  const float* bv = (const float*)d_in[6];
  const float* Wo = (const float*)d_in[7];
  const float* bo = (const float*)d_in[8];
  float* out = (float*)d_out;

  u16* ws  = (u16*)d_ws;                        // ws usage: 48 MB total
  u16* xb  = ws;                                // [4096][1024]
  u16* wqb = xb + (size_t)T_SEQ * DM;           // [1024][1024] each
  u16* wkb = wqb + (size_t)DM * DM;
  u16* wvb = wkb + (size_t)DM * DM;
  u16* wob = wvb + (size_t)DM * DM;
  u16* qbb = wob + (size_t)DM * DM;             // [16][4096][64] (q, pre-scaled 1/8)
  u16* kbb = qbb + (size_t)T_SEQ * DM;          // [16][4096][64]
  u16* vbb = kbb + (size_t)T_SEQ * DM;          // [16][64][4096] (transposed)
  u16* abb = vbb + (size_t)T_SEQ * DM;          // [4096][1024] attn merged

  cvt_kernel<<<(T_SEQ * DM / 8) / 256, 256, 0, stream>>>(x, xb, T_SEQ * DM / 8);
  cvt_kernel<<<(DM * DM / 8) / 256, 256, 0, stream>>>(Wq, wqb, DM * DM / 8);
  cvt_kernel<<<(DM * DM / 8) / 256, 256, 0, stream>>>(Wk, wkb, DM * DM / 8);
  cvt_kernel<<<(DM * DM / 8) / 256, 256, 0, stream>>>(Wv, wvb, DM * DM / 8);
  cvt_kernel<<<(DM * DM / 8) / 256, 256, 0, stream>>>(Wo, wob, DM * DM / 8);

  gemm_qkv<<<dim3(DM / 128, T_SEQ / 128, 3), 256, 0, stream>>>(
      xb, wqb, wkb, wvb, bq, bk, bv, qbb, kbb, vbb);

  attn_kernel<<<dim3(T_SEQ / 64, NH), 256, 0, stream>>>(qbb, kbb, vbb, abb);

  gemm_out<<<dim3(DM / 128, T_SEQ / 128), 256, 0, stream>>>(abb, wob, bo, out);
}

// Round 7
// 243.834 us; speedup vs baseline: 1.5647x; 1.5647x over previous
//
#include <hip/hip_runtime.h>
#include <stdint.h>
#include <math.h>

#define T_SEQ 4096
#define DM 1024
#define NH 16
#define DH 64
#define QSCALE 0.1803368801111137f  // 0.125 * log2(e): softmax done in exp2 domain

typedef unsigned short u16;
typedef __attribute__((ext_vector_type(8))) short bfx8;    // 8 bf16 = 4 VGPR
typedef __attribute__((ext_vector_type(4))) float f4;      // 16x16 MFMA C/D
typedef __attribute__((ext_vector_type(16))) float f16f;   // 32x32 MFMA C/D
typedef __attribute__((ext_vector_type(4))) uint32_t u32x4;

__device__ inline u16 f2bf(float f) {
  uint32_t u = __float_as_uint(f);
  u = (u + 0x7fffu + ((u >> 16) & 1u)) >> 16;
  return (u16)u;
}

__device__ inline uint32_t cvtpk(float lo, float hi) {
  uint32_t r;
  asm("v_cvt_pk_bf16_f32 %0, %1, %2" : "=v"(r) : "v"(lo), "v"(hi));
  return r;
}
// swaps: vdst lanes 32-63 <-> vsrc lanes 0-31 (both modified)
__device__ inline void pl32(uint32_t &a, uint32_t &b) {
  asm volatile("v_permlane32_swap_b32 %0, %1" : "+v"(a), "+v"(b));
}

// async global->LDS, 16B per lane. LDS dest must be uniform-base + lane*16.
__device__ inline void gl_lds16(const void* g, void* l) {
  __builtin_amdgcn_global_load_lds(
      (__attribute__((address_space(1))) uint32_t*)const_cast<void*>(g),
      (__attribute__((address_space(3))) uint32_t*)l, 16, 0, 0);
}

// ---------------- fp32 -> bf16 converts ----------------
__global__ __launch_bounds__(256) void cvt_kernel(const float* __restrict__ src,
                                                  u16* __restrict__ dst, int n8) {
  int i = blockIdx.x * 256 + threadIdx.x;
  if (i >= n8) return;
  const float4* s = (const float4*)src + (size_t)i * 2;
  float4 a = s[0], b = s[1];
  union { u16 u[8]; bfx8 v; } o;
  o.u[0] = f2bf(a.x); o.u[1] = f2bf(a.y); o.u[2] = f2bf(a.z); o.u[3] = f2bf(a.w);
  o.u[4] = f2bf(b.x); o.u[5] = f2bf(b.y); o.u[6] = f2bf(b.z); o.u[7] = f2bf(b.w);
  *(bfx8*)(dst + (size_t)i * 8) = o.v;
}

__global__ __launch_bounds__(256) void cvt4_kernel(
    const float* __restrict__ a, const float* __restrict__ b,
    const float* __restrict__ c, const float* __restrict__ d,
    u16* __restrict__ oa, u16* __restrict__ ob, u16* __restrict__ oc, u16* __restrict__ od) {
  int z = blockIdx.y;
  const float* s = (z == 0) ? a : (z == 1) ? b : (z == 2) ? c : d;
  u16* o = (z == 0) ? oa : (z == 1) ? ob : (z == 2) ? oc : od;
  int i = blockIdx.x * 256 + threadIdx.x;
  const float4* sp = (const float4*)s + (size_t)i * 2;
  float4 x = sp[0], y = sp[1];
  union { u16 u[8]; bfx8 v; } t;
  t.u[0] = f2bf(x.x); t.u[1] = f2bf(x.y); t.u[2] = f2bf(x.z); t.u[3] = f2bf(x.w);
  t.u[4] = f2bf(y.x); t.u[5] = f2bf(y.y); t.u[6] = f2bf(y.z); t.u[7] = f2bf(y.w);
  *(bfx8*)(o + (size_t)i * 8) = t.v;
}

// ---------------- QKV projection GEMM (NT): y = x @ W^T + b ----------------
__global__ __launch_bounds__(256) void gemm_qkv(
    const u16* __restrict__ xb,
    const u16* __restrict__ wq, const u16* __restrict__ wk, const u16* __restrict__ wv,
    const float* __restrict__ bq, const float* __restrict__ bk, const float* __restrict__ bv,
    u16* __restrict__ qo, u16* __restrict__ ko, u16* __restrict__ vo) {
  __shared__ u16 sA[128 * 32];
  __shared__ u16 sB[128 * 32];
  const int mode = blockIdx.z;
  const u16* w = (mode == 0) ? wq : (mode == 1) ? wk : wv;
  const float* bias = (mode == 0) ? bq : (mode == 1) ? bk : bv;
  const int tid = threadIdx.x, lane = tid & 63, wid = tid >> 6;
  const int wr = wid >> 1, wc = wid & 1;
  const int row0 = blockIdx.y * 128, col0 = blockIdx.x * 128;
  f4 acc[4][4] = {};

  for (int kt = 0; kt < DM / 32; ++kt) {
#pragma unroll
    for (int i = 0; i < 2; ++i) {
      int c = i * 4 + wid;
      int r = c * 16 + (lane >> 2);
      int s = (lane & 3) ^ ((r >> 1) & 3);
      gl_lds16(xb + (size_t)(row0 + r) * DM + kt * 32 + s * 8, &sA[c * 512 + lane * 8]);
      gl_lds16(w  + (size_t)(col0 + r) * DM + kt * 32 + s * 8, &sB[c * 512 + lane * 8]);
    }
    __syncthreads();
    bfx8 a[4], b[4];
#pragma unroll
    for (int t = 0; t < 4; ++t) {
      int ra = wr * 64 + t * 16 + (lane & 15);
      a[t] = *(const bfx8*)&sA[ra * 32 + (((lane >> 4) ^ ((ra >> 1) & 3)) * 8)];
      int rb = wc * 64 + t * 16 + (lane & 15);
      b[t] = *(const bfx8*)&sB[rb * 32 + (((lane >> 4) ^ ((rb >> 1) & 3)) * 8)];
    }
#pragma unroll
    for (int mt = 0; mt < 4; ++mt)
#pragma unroll
      for (int nt = 0; nt < 4; ++nt)
        acc[mt][nt] = __builtin_amdgcn_mfma_f32_16x16x32_bf16(a[mt], b[nt], acc[mt][nt], 0, 0, 0);
    __syncthreads();
  }

#pragma unroll
  for (int mt = 0; mt < 4; ++mt) {
#pragma unroll
    for (int nt = 0; nt < 4; ++nt) {
      int n = col0 + wc * 64 + nt * 16 + (lane & 15);
      float bv_ = bias[n];
      int h = n >> 6, d = n & 63;
#pragma unroll
      for (int r = 0; r < 4; ++r) {
        int mrow = row0 + wr * 64 + mt * 16 + (lane >> 4) * 4 + r;
        float v = acc[mt][nt][r] + bv_;
        if (mode == 0)      qo[(size_t)h * (T_SEQ * DH) + (size_t)mrow * DH + d] = f2bf(v * QSCALE);
        else if (mode == 1) ko[(size_t)h * (T_SEQ * DH) + (size_t)mrow * DH + d] = f2bf(v);
        else                vo[(size_t)h * (DH * T_SEQ) + (size_t)d * T_SEQ + mrow] = f2bf(v);
      }
    }
  }
}

// ---------------- output projection GEMM: out = ao @ Wo^T + bo (fp32 out) ----------------
__global__ __launch_bounds__(256) void gemm_out(
    const u16* __restrict__ ab, const u16* __restrict__ wo,
    const float* __restrict__ bo, float* __restrict__ out) {
  __shared__ u16 sA[128 * 32];
  __shared__ u16 sB[128 * 32];
  const int tid = threadIdx.x, lane = tid & 63, wid = tid >> 6;
  const int wr = wid >> 1, wc = wid & 1;
  const int row0 = blockIdx.y * 128, col0 = blockIdx.x * 128;
  f4 acc[4][4] = {};

  for (int kt = 0; kt < DM / 32; ++kt) {
#pragma unroll
    for (int i = 0; i < 2; ++i) {
      int c = i * 4 + wid;
      int r = c * 16 + (lane >> 2);
      int s = (lane & 3) ^ ((r >> 1) & 3);
      gl_lds16(ab + (size_t)(row0 + r) * DM + kt * 32 + s * 8, &sA[c * 512 + lane * 8]);
      gl_lds16(wo + (size_t)(col0 + r) * DM + kt * 32 + s * 8, &sB[c * 512 + lane * 8]);
    }
    __syncthreads();
    bfx8 a[4], b[4];
#pragma unroll
    for (int t = 0; t < 4; ++t) {
      int ra = wr * 64 + t * 16 + (lane & 15);
      a[t] = *(const bfx8*)&sA[ra * 32 + (((lane >> 4) ^ ((ra >> 1) & 3)) * 8)];
      int rb = wc * 64 + t * 16 + (lane & 15);
      b[t] = *(const bfx8*)&sB[rb * 32 + (((lane >> 4) ^ ((rb >> 1) & 3)) * 8)];
    }
#pragma unroll
    for (int mt = 0; mt < 4; ++mt)
#pragma unroll
      for (int nt = 0; nt < 4; ++nt)
        acc[mt][nt] = __builtin_amdgcn_mfma_f32_16x16x32_bf16(a[mt], b[nt], acc[mt][nt], 0, 0, 0);
    __syncthreads();
  }

#pragma unroll
  for (int mt = 0; mt < 4; ++mt) {
#pragma unroll
    for (int nt = 0; nt < 4; ++nt) {
      int n = col0 + wc * 64 + nt * 16 + (lane & 15);
      float bv_ = bo[n];
#pragma unroll
      for (int r = 0; r < 4; ++r) {
        int mrow = row0 + wr * 64 + mt * 16 + (lane >> 4) * 4 + r;
        out[(size_t)mrow * DM + n] = acc[mt][nt][r] + bv_;
      }
    }
  }
}

// ---------------- flash attention: 8 waves x QBLK=32, 32x32x16, swapped QK^T ----------------
// S^T = mfma(K, Q): lane q=lane&31 holds 32 P values in-register (no LDS P).
// O^T = mfma(V^T, P^T): softmax state stays per-lane. Double-buffered K/V staging.
__global__ __launch_bounds__(512, 2) void attn_kernel(
    const u16* __restrict__ qb, const u16* __restrict__ kb,
    const u16* __restrict__ vb, u16* __restrict__ ao) {
  __shared__ u16 sK[2][64 * 64];
  __shared__ u16 sV[2][64 * 64];
  const int tid = threadIdx.x, lane = tid & 63, wid = tid >> 6;
  const int hi = lane >> 5, q32 = lane & 31;
  const int bid = blockIdx.x;
  // XCD-aware: 2 heads per XCD so K/V (2MB) fits the per-XCD L2
  const int h = (bid & 7) * 2 + ((bid >> 3) & 1);
  const int qr0 = (bid >> 4) * 256 + wid * 32;
  const size_t hoff = (size_t)h * ((size_t)T_SEQ * DH);

  // Q fragments (B-operand): Q[q=lane&31][d = 16*ds + 8*hi + j]
  bfx8 qf0, qf1, qf2, qf3;
  {
    const u16* qp = qb + hoff + (size_t)(qr0 + q32) * DH + hi * 8;
    qf0 = *(const bfx8*)(qp);
    qf1 = *(const bfx8*)(qp + 16);
    qf2 = *(const bfx8*)(qp + 32);
    qf3 = *(const bfx8*)(qp + 48);
  }

  f16f o0 = {}, o1 = {};          // O^T accum: d rows 0-31 / 32-63, col q=lane&31
  float m = -INFINITY, l = 0.f;

  // staging: thread covers LDS row sr (0..63), 16B slot (tid&7); XOR-swizzled source
  const int sr = tid >> 3, ssl = (tid & 7) ^ (sr & 7);
  const u16* kg = kb + hoff + (size_t)sr * DH + ssl * 8;
  const u16* vg = vb + hoff + (size_t)sr * T_SEQ + ssl * 8;
  u16* dK0 = &sK[0][tid * 8]; u16* dK1 = &sK[1][tid * 8];
  u16* dV0 = &sV[0][tid * 8]; u16* dV1 = &sV[1][tid * 8];

  gl_lds16(kg, dK0);
  gl_lds16(vg, dV0);
  __syncthreads();

  const int NT = T_SEQ / 64;
  const int x0 = (q32 & 7) * 8;  // swizzle term (rows r and r+32 share r&7)
  for (int kt = 0; kt < NT; ++kt) {
    const u16* Kc = (kt & 1) ? sK[1] : sK[0];
    const u16* Vc = (kt & 1) ? sV[1] : sV[0];
    if (kt + 1 < NT) {  // prefetch next tile into other buffer
      gl_lds16(kg + (size_t)(kt + 1) * 64 * DH, (kt & 1) ? dK0 : dK1);
      gl_lds16(vg + (size_t)(kt + 1) * 64,     (kt & 1) ? dV0 : dV1);
    }

    // S^T = K Q^T : s0 = k rows 0-31, s1 = k rows 32-63 (col = q = lane&31)
    f16f s0 = {}, s1 = {};
    {
      const int c0 = q32 * 64, c1 = (32 + q32) * 64;
#define QKSTEP(ds, QF)                                                              \
      {                                                                             \
        bfx8 kf0 = *(const bfx8*)&Kc[c0 + (((2 * ds + hi) * 8) ^ x0)];              \
        s0 = __builtin_amdgcn_mfma_f32_32x32x16_bf16(kf0, QF, s0, 0, 0, 0);         \
        bfx8 kf1 = *(const bfx8*)&Kc[c1 + (((2 * ds + hi) * 8) ^ x0)];              \
        s1 = __builtin_amdgcn_mfma_f32_32x32x16_bf16(kf1, QF, s1, 0, 0, 0);         \
      }
      QKSTEP(0, qf0) QKSTEP(1, qf1) QKSTEP(2, qf2) QKSTEP(3, qf3)
#undef QKSTEP
    }

    // online softmax (exp2 domain), all state per-lane (q = lane&31)
    float tm = fmaxf(s0[0], s1[0]);
#pragma unroll
    for (int r = 1; r < 16; ++r) tm = fmaxf(tm, fmaxf(s0[r], s1[r]));
    tm = fmaxf(tm, __shfl_xor(tm, 32));
    float mn = fmaxf(m, tm);
    float fsc = __builtin_amdgcn_exp2f(m - mn);
    m = mn;
    float ps = 0.f;
#pragma unroll
    for (int r = 0; r < 16; ++r) { s0[r] = __builtin_amdgcn_exp2f(s0[r] - mn); ps += s0[r]; }
#pragma unroll
    for (int r = 0; r < 16; ++r) { s1[r] = __builtin_amdgcn_exp2f(s1[r] - mn); ps += s1[r]; }
    ps += __shfl_xor(ps, 32);
    l = l * fsc + ps;
#pragma unroll
    for (int r = 0; r < 16; ++r) { o0[r] *= fsc; o1[r] *= fsc; }

    // P(f32, S^T layout) -> bf16 PV fragments via cvt_pk + permlane32_swap (T12)
    uint32_t a0, a1, a2, a3;
    bfx8 pa0, pa1, pa2, pa3;
#define PACK(SS, i0, PA)                                                     \
    a0 = cvtpk(SS[i0 + 0], SS[i0 + 1]); a1 = cvtpk(SS[i0 + 2], SS[i0 + 3]);  \
    a2 = cvtpk(SS[i0 + 4], SS[i0 + 5]); a3 = cvtpk(SS[i0 + 6], SS[i0 + 7]);  \
    pl32(a0, a2); pl32(a1, a3);                                              \
    { u32x4 t_; t_[0] = a0; t_[1] = a1; t_[2] = a2; t_[3] = a3;              \
      PA = __builtin_bit_cast(bfx8, t_); }
    PACK(s0, 0, pa0) PACK(s0, 8, pa1) PACK(s1, 0, pa2) PACK(s1, 8, pa3)
#undef PACK

    // O^T += V^T P^T : A = V^T rows (d), B = P fragments
    {
      const int d0 = q32 * 64, d1 = (32 + q32) * 64;
#define PVSTEP(ks, PA)                                                              \
      {                                                                             \
        bfx8 vf0 = *(const bfx8*)&Vc[d0 + (((2 * ks + hi) * 8) ^ x0)];              \
        o0 = __builtin_amdgcn_mfma_f32_32x32x16_bf16(vf0, PA, o0, 0, 0, 0);         \
        bfx8 vf1 = *(const bfx8*)&Vc[d1 + (((2 * ks + hi) * 8) ^ x0)];              \
        o1 = __builtin_amdgcn_mfma_f32_32x32x16_bf16(vf1, PA, o1, 0, 0, 0);         \
      }
      PVSTEP(0, pa0) PVSTEP(1, pa1) PVSTEP(2, pa2) PVSTEP(3, pa3)
#undef PVSTEP
    }
    __syncthreads();  // staged tile kt+1 ready; all waves done reading tile kt
  }

  // epilogue: O^T[d][q] -> ao[t][h*64+d], normalize by l
  float inv = 1.0f / l;
  u16* orow = ao + (size_t)(qr0 + q32) * DM + h * DH;
#pragma unroll
  for (int r = 0; r < 16; ++r) {
    int d0 = (r & 3) + 8 * (r >> 2) + 4 * hi;
    orow[d0]      = f2bf(o0[r] * inv);
    orow[32 + d0] = f2bf(o1[r] * inv);
  }
}

extern "C" void kernel_launch(void* const* d_in, const int* in_sizes, int n_in,
                              void* d_out, int out_size, void* d_ws, size_t ws_size,
                              hipStream_t stream) {
  const float* x  = (const float*)d_in[0];
  const float* Wq = (const float*)d_in[1];
  const float* bq = (const float*)d_in[2];
  const float* Wk = (const float*)d_in[3];
  const float* bk = (const float*)d_in[4];
  const float* Wv = (const float*)d_in[5];
  const float* bv = (const float*)d_in[6];
  const float* Wo = (const float*)d_in[7];
  const float* bo = (const float*)d_in[8];
  float* out = (float*)d_out;

  u16* ws  = (u16*)d_ws;
  u16* xb  = ws;                                // [4096][1024]
  u16* wqb = xb + (size_t)T_SEQ * DM;           // [1024][1024] each
  u16* wkb = wqb + (size_t)DM * DM;
  u16* wvb = wkb + (size_t)DM * DM;
  u16* wob = wvb + (size_t)DM * DM;
  u16* qbb = wob + (size_t)DM * DM;             // [16][4096][64] (q, pre-scaled)
  u16* kbb = qbb + (size_t)T_SEQ * DM;          // [16][4096][64]
  u16* vbb = kbb + (size_t)T_SEQ * DM;          // [16][64][4096] (transposed)
  u16* abb = vbb + (size_t)T_SEQ * DM;          // [4096][1024] attn merged

  cvt_kernel<<<(T_SEQ * DM / 8) / 256, 256, 0, stream>>>(x, xb, T_SEQ * DM / 8);
  cvt4_kernel<<<dim3((DM * DM / 8) / 256, 4), 256, 0, stream>>>(
      Wq, Wk, Wv, Wo, wqb, wkb, wvb, wob);

  gemm_qkv<<<dim3(DM / 128, T_SEQ / 128, 3), 256, 0, stream>>>(
      xb, wqb, wkb, wvb, bq, bk, bv, qbb, kbb, vbb);

  attn_kernel<<<256, 512, 0, stream>>>(qbb, kbb, vbb, abb);

  gemm_out<<<dim3(DM / 128, T_SEQ / 128), 256, 0, stream>>>(abb, wob, bo, out);
}